// Round 6
// baseline (141.548 us; speedup 1.0000x reference)
//
#include <hip/hip_runtime.h>

// LowFreqPenaltyLoss: mean(|truncated 2-D DCT (8x8) of each 256x256 image|)
// delta: [256,3,256,256] f32 -> scalar f32.
// Basis C[k,n] = 2*cos(pi*(2n+1)*k/512), identical for H and W.
// Per image: u[w][i] = sum_h C[i,h]*X[h,w]; low[i,j] = sum_w C[j,w]*u[w][i].
//
// R6 = R4 (1536 half-image blocks, dword stride-64 loads — best so far) +
//  (a) low-VGPR epilogue: cross-wave u-slab in LDS instead of per-thread
//      v[64]+butterfly  (~150 -> ~90 VGPR, 12 -> 16+ waves/CU), and
//  (b) fused finish: threadfence-reduction winner block per image, ws
//      accumulator, last winner stores out — no second kernel.

#define INV_COUNT (1.0f / 49152.0f)  // 256*3*8*8
#define NBLK 1536
#define CTRL_OFF (NBLK * 64)         // float index of control region in ws
// ctrl layout (floats): [0..767] int cnt per image, [768] float accum,
//                       [769] int done-counter.  770 words, memset to 0.

__global__ __launch_bounds__(256, 4) void lowfreq_main(
    const float* __restrict__ delta, float* __restrict__ ws,
    float* __restrict__ out)
{
    __shared__ __align__(16) float c_row[256][8];   // basis, broadcast by row h
    __shared__ __align__(16) float c_col[8][260];   // transposed, 260: bank spread
    __shared__ __align__(16) float u_lds[8][260];   // u[i][w] summed over waves
    __shared__ float pacc[4][64];                   // per-wave slot partials

    const int t = threadIdx.x;
    const int wave = t >> 6;
    const int lane = t & 63;
    const int bid = blockIdx.x;
    const int img = bid >> 1;        // (n,c) image index
    const int half = bid & 1;        // rows [0,128) or [128,256)

    // Phase 0: DCT-II basis row t via Chebyshev recurrence (1 cosf).
    {
        const float a = 3.14159265358979323846f * (2.0f * (float)t + 1.0f)
                        * (1.0f / 512.0f);
        const float ca = cosf(a);
        float ckm1 = 1.0f, ck = ca;
        c_row[t][0] = 2.0f;       c_col[0][t] = 2.0f;
        c_row[t][1] = 2.0f * ca;  c_col[1][t] = 2.0f * ca;
        #pragma unroll
        for (int k = 2; k < 8; ++k) {
            const float cn = 2.0f * ca * ck - ckm1;
            ckm1 = ck; ck = cn;
            c_row[t][k] = 2.0f * cn;
            c_col[k][t] = 2.0f * cn;
        }
    }
    __syncthreads();

    // Phase 1: wave streams rows [half*128 + 32*wave, +32); thread owns
    // columns {lane, lane+64, lane+128, lane+192} (dword, stride 64 — the
    // pattern that benched fastest).
    const int row0 = (half << 7) + (wave << 5);
    const float* gp = delta + (size_t)img * 65536 + (size_t)row0 * 256 + lane;

    float u[4][8];
    #pragma unroll
    for (int c = 0; c < 4; ++c)
        #pragma unroll
        for (int i = 0; i < 8; ++i) u[c][i] = 0.0f;

    #pragma unroll 4
    for (int r = 0; r < 32; ++r) {
        const int h = row0 + r;
        const float x0 = gp[r * 256 + 0];
        const float x1 = gp[r * 256 + 64];
        const float x2 = gp[r * 256 + 128];
        const float x3 = gp[r * 256 + 192];
        const float4 cA = *reinterpret_cast<const float4*>(&c_row[h][0]);
        const float4 cB = *reinterpret_cast<const float4*>(&c_row[h][4]);
        const float cc[8] = {cA.x, cA.y, cA.z, cA.w, cB.x, cB.y, cB.z, cB.w};
        #pragma unroll
        for (int i = 0; i < 8; ++i) {
            u[0][i] = fmaf(cc[i], x0, u[0][i]);
            u[1][i] = fmaf(cc[i], x1, u[1][i]);
            u[2][i] = fmaf(cc[i], x2, u[2][i]);
            u[3][i] = fmaf(cc[i], x3, u[3][i]);
        }
    }

    // Phase 2: staged cross-wave accumulation into u_lds[i][w], w = c*64+lane.
    // Consecutive lanes -> consecutive addresses: conflict-free (2-way free).
    #pragma unroll
    for (int s = 0; s < 4; ++s) {
        if (wave == s) {
            #pragma unroll
            for (int i = 0; i < 8; ++i)
                #pragma unroll
                for (int c = 0; c < 4; ++c) {
                    const int w = (c << 6) + lane;
                    if (s == 0) u_lds[i][w] = u[c][i];
                    else        u_lds[i][w] += u[c][i];
                }
        }
        __syncthreads();
    }

    // Phase 3: lane owns slot (i,j); wave contracts w in [64*wave, +64).
    // float4 reads; banks = (4i + w) mod 32 (260 % 32 == 4): 8 address
    // groups x 8-lane broadcast, all 32 banks covered -> conflict-free.
    {
        const int i = lane >> 3;
        const int j = lane & 7;
        const int w0 = wave << 6;
        float acc = 0.0f;
        #pragma unroll
        for (int k = 0; k < 16; ++k) {
            const float4 uv = *reinterpret_cast<const float4*>(&u_lds[i][w0 + (k << 2)]);
            const float4 cv = *reinterpret_cast<const float4*>(&c_col[j][w0 + (k << 2)]);
            acc = fmaf(uv.x, cv.x, acc);
            acc = fmaf(uv.y, cv.y, acc);
            acc = fmaf(uv.z, cv.z, acc);
            acc = fmaf(uv.w, cv.w, acc);
        }
        pacc[wave][lane] = acc;
    }
    __syncthreads();

    // Phase 4: wave 0 combines waves -> pre-abs half-image partial -> ws;
    // second-arriving block per image finishes: pair, abs, sum, accumulate.
    if (wave == 0) {
        const float s4 = pacc[0][lane] + pacc[1][lane] + pacc[2][lane] + pacc[3][lane];
        ws[(size_t)bid * 64 + lane] = s4;
        __threadfence();                       // release partials
        int arrived = 0;
        if (lane == 0)
            arrived = atomicAdd((int*)(ws + CTRL_OFF) + img, 1);
        arrived = __shfl(arrived, 0, 64);
        if (arrived == 1) {                    // winner: sibling data visible
            __threadfence();                   // acquire
            const float oth = ws[(size_t)(bid ^ 1) * 64 + lane];
            float a = fabsf(s4 + oth);
            #pragma unroll
            for (int m = 1; m < 64; m <<= 1) a += __shfl_xor(a, m, 64);
            if (lane == 0) {
                float* accum = ws + CTRL_OFF + 768;
                int* done = (int*)(ws + CTRL_OFF) + 769;
                atomicAdd(accum, a);
                __threadfence();
                if (atomicAdd(done, 1) == 767) {   // 768th winner: finish
                    __threadfence();
                    out[0] = atomicAdd(accum, 0.0f) * INV_COUNT;
                }
            }
        }
    }
}

extern "C" void kernel_launch(void* const* d_in, const int* in_sizes, int n_in,
                              void* d_out, int out_size, void* d_ws, size_t ws_size,
                              hipStream_t stream)
{
    const float* delta = (const float*)d_in[0];
    float* out = (float*)d_out;
    float* ws = (float*)d_ws;  // partials 393216 B + 3080 B control
    hipMemsetAsync((char*)d_ws + (size_t)CTRL_OFF * 4, 0, 770 * 4, stream);
    lowfreq_main<<<NBLK, 256, 0, stream>>>(delta, ws, out);
}

// Round 7
// 48.759 us; speedup vs baseline: 2.9030x; 2.9030x over previous
//
#include <hip/hip_runtime.h>

// LowFreqPenaltyLoss: mean(|truncated 2-D DCT (8x8) of each 256x256 image|)
// delta: [256,3,256,256] f32 -> scalar f32.
// Basis C[k,n] = 2*cos(pi*(2n+1)*k/512), identical for H and W.
// Per image: u[w][i] = sum_h C[i,h]*X[h,w]; low[i,j] = sum_w C[j,w]*u[w][i].
//
// R7: one image per block (768 blocks), single kernel, single atomicAdd.
// Low-VGPR epilogue via LDS u-slab (no v[64] butterfly): VGPR < 128 so all
// 768 blocks are co-resident (>=3 blocks/CU) -> one scheduling round, no
// tail, no ws traffic, no reduce dispatch. Plain __launch_bounds__(256):
// the (256,4) min-waves arg in R6 drove the allocator to 44 VGPR + scratch
// spill (catastrophic); do not reintroduce it.

#define INV_COUNT (1.0f / 49152.0f)  // 256*3*8*8

__global__ __launch_bounds__(256) void lowfreq_main(
    const float* __restrict__ delta, float* __restrict__ out)
{
    __shared__ __align__(16) float c_row[256][8];   // basis, broadcast by row h
    __shared__ __align__(16) float c_col[8][260];   // transposed; 260 -> bank spread
    __shared__ __align__(16) float u_lds[8][260];   // u[i][w] summed over waves
    __shared__ float pacc[4][64];                   // per-wave slot partials

    const int t = threadIdx.x;
    const int wave = t >> 6;
    const int lane = t & 63;

    // Phase 0: DCT-II basis row t via Chebyshev recurrence (1 cosf).
    {
        const float a = 3.14159265358979323846f * (2.0f * (float)t + 1.0f)
                        * (1.0f / 512.0f);
        const float ca = cosf(a);
        float ckm1 = 1.0f, ck = ca;
        c_row[t][0] = 2.0f;       c_col[0][t] = 2.0f;
        c_row[t][1] = 2.0f * ca;  c_col[1][t] = 2.0f * ca;
        #pragma unroll
        for (int k = 2; k < 8; ++k) {
            const float cn = 2.0f * ca * ck - ckm1;
            ckm1 = ck; ck = cn;
            c_row[t][k] = 2.0f * cn;
            c_col[k][t] = 2.0f * cn;
        }
    }
    __syncthreads();

    // Phase 1: wave owns rows [64*wave, 64*wave+64); thread owns columns
    // {lane, lane+64, lane+128, lane+192} (dword loads, stride 64 — the
    // pattern that benched fastest in R0/R4).
    const int row0 = wave << 6;
    const float* gp = delta + (size_t)blockIdx.x * 65536
                            + (size_t)row0 * 256 + lane;

    float u[4][8];
    #pragma unroll
    for (int c = 0; c < 4; ++c)
        #pragma unroll
        for (int i = 0; i < 8; ++i) u[c][i] = 0.0f;

    #pragma unroll 4
    for (int r = 0; r < 64; ++r) {
        const int h = row0 + r;
        const float x0 = gp[r * 256 + 0];
        const float x1 = gp[r * 256 + 64];
        const float x2 = gp[r * 256 + 128];
        const float x3 = gp[r * 256 + 192];
        const float4 cA = *reinterpret_cast<const float4*>(&c_row[h][0]);
        const float4 cB = *reinterpret_cast<const float4*>(&c_row[h][4]);
        const float cc[8] = {cA.x, cA.y, cA.z, cA.w, cB.x, cB.y, cB.z, cB.w};
        #pragma unroll
        for (int i = 0; i < 8; ++i) {
            u[0][i] = fmaf(cc[i], x0, u[0][i]);
            u[1][i] = fmaf(cc[i], x1, u[1][i]);
            u[2][i] = fmaf(cc[i], x2, u[2][i]);
            u[3][i] = fmaf(cc[i], x3, u[3][i]);
        }
    }

    // Phase 2: staged cross-wave accumulation into u_lds[i][w], w = c*64+lane.
    // Consecutive lanes -> consecutive words: 2 lanes/bank = free.
    #pragma unroll
    for (int s = 0; s < 4; ++s) {
        if (wave == s) {
            #pragma unroll
            for (int i = 0; i < 8; ++i)
                #pragma unroll
                for (int c = 0; c < 4; ++c) {
                    const int w = (c << 6) + lane;
                    if (s == 0) u_lds[i][w] = u[c][i];
                    else        u_lds[i][w] += u[c][i];
                }
        }
        __syncthreads();
    }

    // Phase 3: lane owns slot (i,j) = (lane>>3, lane&7); wave contracts
    // w in [64*wave, +64). float4 reads; stride 260 % 32 == 4 spreads the
    // 8 i-groups (and 8 j-groups) across distinct banks; 8-lane broadcasts.
    {
        const int i = lane >> 3;
        const int j = lane & 7;
        const int w0 = wave << 6;
        float acc = 0.0f;
        #pragma unroll
        for (int k = 0; k < 16; ++k) {
            const float4 uv = *reinterpret_cast<const float4*>(&u_lds[i][w0 + (k << 2)]);
            const float4 cv = *reinterpret_cast<const float4*>(&c_col[j][w0 + (k << 2)]);
            acc = fmaf(uv.x, cv.x, acc);
            acc = fmaf(uv.y, cv.y, acc);
            acc = fmaf(uv.z, cv.z, acc);
            acc = fmaf(uv.w, cv.w, acc);
        }
        pacc[wave][lane] = acc;
    }
    __syncthreads();

    // Phase 4: combine 4 waves per slot, abs, wave-sum, one atomic per block.
    if (wave == 0) {
        const float s4 = pacc[0][lane] + pacc[1][lane]
                       + pacc[2][lane] + pacc[3][lane];
        float a = fabsf(s4);
        #pragma unroll
        for (int m = 1; m < 64; m <<= 1) a += __shfl_xor(a, m, 64);
        if (lane == 0) atomicAdd(out, a * INV_COUNT);
    }
}

extern "C" void kernel_launch(void* const* d_in, const int* in_sizes, int n_in,
                              void* d_out, int out_size, void* d_ws, size_t ws_size,
                              hipStream_t stream)
{
    const float* delta = (const float*)d_in[0];
    float* out = (float*)d_out;
    hipMemsetAsync(out, 0, 4, stream);
    lowfreq_main<<<768, 256, 0, stream>>>(delta, out);
}

// Round 8
// 41.535 us; speedup vs baseline: 3.4080x; 1.1739x over previous
//
#include <hip/hip_runtime.h>

// LowFreqPenaltyLoss: mean(|truncated 2-D DCT (8x8) of each 256x256 image|)
// delta: [256,3,256,256] f32 -> scalar f32.
// Basis C[k,n] = 2*cos(pi*(2n+1)*k/512), identical for H and W.
// Per image: u[w][i] = sum_h C[i,h]*X[h,w]; low[i,j] = sum_w C[j,w]*u[w][i].
//
// R8 = R4 structure (1536 half-image blocks @ 256 thr, two kernels, dword
// stride-64 loads) + low-VGPR LDS-slab epilogue (no v[64] butterfly ->
// ~90 VGPR, LDS 25.6KB -> up to 6 blocks/CU vs R4's 3) + software-pipelined
// loads (first batch issued before the basis/barrier; 4-row double buffer).
// R6 lesson: no min-waves arg in __launch_bounds__ (spill trap), no
// __threadfence winner scheme (XCD L2 writeback storm).

#define INV_COUNT (1.0f / 49152.0f)  // 256*3*8*8

__global__ __launch_bounds__(256) void lowfreq_main(
    const float* __restrict__ delta, float* __restrict__ ws,
    float* __restrict__ out)
{
    __shared__ __align__(16) float c_row[256][8];   // basis, broadcast by row h
    __shared__ __align__(16) float c_col[8][260];   // transposed; 260 -> bank spread
    __shared__ __align__(16) float u_lds[8][260];   // u[i][w] summed over waves
    __shared__ float pacc[4][64];                   // per-wave slot partials

    const int t = threadIdx.x;
    const int wave = t >> 6;
    const int lane = t & 63;
    const int bid = blockIdx.x;
    const int img = bid >> 1;        // (n,c) image index
    const int half = bid & 1;        // rows [0,128) or [128,256)

    // Wave streams rows [half*128 + 32*wave, +32); thread owns columns
    // {lane, lane+64, lane+128, lane+192} (dword loads, stride 64).
    const int row0 = (half << 7) + (wave << 5);
    const float* gp = delta + (size_t)img * 65536 + (size_t)row0 * 256 + lane;

    // Issue batch 0 loads BEFORE the basis compute + barrier (independent).
    float x[4][4];
    #pragma unroll
    for (int rr = 0; rr < 4; ++rr) {
        const float* p = gp + (size_t)rr * 256;
        x[rr][0] = p[0];  x[rr][1] = p[64];
        x[rr][2] = p[128]; x[rr][3] = p[192];
    }

    // Phase 0: DCT-II basis row t via Chebyshev recurrence (1 cosf).
    {
        const float a = 3.14159265358979323846f * (2.0f * (float)t + 1.0f)
                        * (1.0f / 512.0f);
        const float ca = cosf(a);
        float ckm1 = 1.0f, ck = ca;
        c_row[t][0] = 2.0f;       c_col[0][t] = 2.0f;
        c_row[t][1] = 2.0f * ca;  c_col[1][t] = 2.0f * ca;
        #pragma unroll
        for (int k = 2; k < 8; ++k) {
            const float cn = 2.0f * ca * ck - ckm1;
            ckm1 = ck; ck = cn;
            c_row[t][k] = 2.0f * cn;
            c_col[k][t] = 2.0f * cn;
        }
    }
    __syncthreads();

    float u[4][8];
    #pragma unroll
    for (int c = 0; c < 4; ++c)
        #pragma unroll
        for (int i = 0; i < 8; ++i) u[c][i] = 0.0f;

    // Phase 1: 8 batches x 4 rows, double-buffered (load rb+1 while
    // computing rb): 16 independent dword loads in flight per thread.
    #pragma unroll
    for (int rb = 0; rb < 8; ++rb) {
        float xn[4][4];
        if (rb < 7) {
            #pragma unroll
            for (int rr = 0; rr < 4; ++rr) {
                const float* p = gp + (size_t)((rb + 1) * 4 + rr) * 256;
                xn[rr][0] = p[0];  xn[rr][1] = p[64];
                xn[rr][2] = p[128]; xn[rr][3] = p[192];
            }
        }
        #pragma unroll
        for (int rr = 0; rr < 4; ++rr) {
            const int h = row0 + (rb << 2) + rr;
            const float4 cA = *reinterpret_cast<const float4*>(&c_row[h][0]);
            const float4 cB = *reinterpret_cast<const float4*>(&c_row[h][4]);
            const float cc[8] = {cA.x, cA.y, cA.z, cA.w, cB.x, cB.y, cB.z, cB.w};
            #pragma unroll
            for (int i = 0; i < 8; ++i) {
                u[0][i] = fmaf(cc[i], x[rr][0], u[0][i]);
                u[1][i] = fmaf(cc[i], x[rr][1], u[1][i]);
                u[2][i] = fmaf(cc[i], x[rr][2], u[2][i]);
                u[3][i] = fmaf(cc[i], x[rr][3], u[3][i]);
            }
        }
        if (rb < 7) {
            #pragma unroll
            for (int rr = 0; rr < 4; ++rr)
                #pragma unroll
                for (int c = 0; c < 4; ++c)
                    x[rr][c] = xn[rr][c];
        }
    }

    // Phase 2: staged cross-wave accumulation into u_lds[i][w], w = c*64+lane.
    // Consecutive lanes -> consecutive words: 2 lanes/bank = free.
    #pragma unroll
    for (int s = 0; s < 4; ++s) {
        if (wave == s) {
            #pragma unroll
            for (int i = 0; i < 8; ++i)
                #pragma unroll
                for (int c = 0; c < 4; ++c) {
                    const int w = (c << 6) + lane;
                    if (s == 0) u_lds[i][w] = u[c][i];
                    else        u_lds[i][w] += u[c][i];
                }
        }
        __syncthreads();
    }

    // Phase 3: lane owns slot (i,j) = (lane>>3, lane&7); wave contracts
    // w in [64*wave, +64). 8 b128 address-groups/instr, 8-lane broadcast,
    // stride 260 (mod 32 == 4) -> all 32 banks covered, conflict-free.
    {
        const int i = lane >> 3;
        const int j = lane & 7;
        const int w0 = wave << 6;
        float acc = 0.0f;
        #pragma unroll
        for (int k = 0; k < 16; ++k) {
            const float4 uv = *reinterpret_cast<const float4*>(&u_lds[i][w0 + (k << 2)]);
            const float4 cv = *reinterpret_cast<const float4*>(&c_col[j][w0 + (k << 2)]);
            acc = fmaf(uv.x, cv.x, acc);
            acc = fmaf(uv.y, cv.y, acc);
            acc = fmaf(uv.z, cv.z, acc);
            acc = fmaf(uv.w, cv.w, acc);
        }
        pacc[wave][lane] = acc;
    }
    __syncthreads();

    // Phase 4: wave 0 combines waves -> PRE-ABS half-image partial -> ws.
    if (wave == 0) {
        const float s4 = pacc[0][lane] + pacc[1][lane]
                       + pacc[2][lane] + pacc[3][lane];
        ws[(size_t)bid * 64 + lane] = s4;
        if (bid == 0 && lane == 0) out[0] = 0.0f;  // ordered before reduce
    }
}

// Pair the two half-image partials, abs, sum all 49152 slots into out.
__global__ __launch_bounds__(256) void lowfreq_reduce(
    const float* __restrict__ ws, float* __restrict__ out)
{
    __shared__ float acc[4];
    const int t = threadIdx.x;
    const int wave = t >> 6;
    const int lane = t & 63;
    const int g = blockIdx.x * 256 + t;       // 192*256 = 49152 = 768*64
    const int img = g >> 6;
    const int slot = g & 63;

    const float s = ws[(size_t)(2 * img) * 64 + slot]
                  + ws[(size_t)(2 * img + 1) * 64 + slot];
    float a = fabsf(s);
    #pragma unroll
    for (int m = 1; m < 64; m <<= 1) a += __shfl_xor(a, m, 64);
    if (lane == 0) acc[wave] = a;
    __syncthreads();
    if (t == 0)
        atomicAdd(out, (acc[0] + acc[1] + acc[2] + acc[3]) * INV_COUNT);
}

extern "C" void kernel_launch(void* const* d_in, const int* in_sizes, int n_in,
                              void* d_out, int out_size, void* d_ws, size_t ws_size,
                              hipStream_t stream)
{
    const float* delta = (const float*)d_in[0];
    float* out = (float*)d_out;
    float* ws = (float*)d_ws;  // 1536*64*4 B = 393 KB
    lowfreq_main<<<1536, 256, 0, stream>>>(delta, ws, out);
    lowfreq_reduce<<<192, 256, 0, stream>>>(ws, out);
}